// Round 1
// baseline (367.195 us; speedup 1.0000x reference)
//
#include <hip/hip_runtime.h>
#include <hip/hip_bf16.h>

#define DEVI __device__ __forceinline__

typedef float f32x4 __attribute__((ext_vector_type(4)));
typedef short bf16x8 __attribute__((ext_vector_type(8)));
typedef int i32x4 __attribute__((ext_vector_type(4)));

constexpr int BATCH = 4;
constexpr int SEQ   = 2048;
constexpr int DIM   = 1024;
constexpr int NH    = 16;
constexpr int HD    = 64;
constexpr int TD    = 3 * DIM;       // 3072
constexpr int MTOT  = BATCH * SEQ;   // 8192

DEVI unsigned short f2bf(float f) {
    union { float f; unsigned int u; } x; x.f = f;
    unsigned int u = x.u;
    unsigned int lsb = (u >> 16) & 1u;
    return (unsigned short)((u + 0x7FFFu + lsb) >> 16);
}

DEVI void gload_lds16(const unsigned short* gsrc, unsigned short* ldst) {
    __builtin_amdgcn_global_load_lds(
        (const __attribute__((address_space(1))) void*)gsrc,
        (__attribute__((address_space(3))) void*)ldst,
        16, 0, 0);
}

// ---------------- convert f32 -> bf16 ----------------
__global__ void cvt_kernel(const float* __restrict__ in, unsigned short* __restrict__ out, int n4) {
    int i = blockIdx.x * blockDim.x + threadIdx.x;
    int stride = gridDim.x * blockDim.x;
    for (; i < n4; i += stride) {
        float4 v = reinterpret_cast<const float4*>(in)[i];
        ushort4 o;
        o.x = f2bf(v.x); o.y = f2bf(v.y); o.z = f2bf(v.z); o.w = f2bf(v.w);
        reinterpret_cast<ushort4*>(out)[i] = o;
    }
}

// ---------------- transpose f32 [R][C] -> bf16 [C][R] ----------------
__global__ void transp_kernel(const float* __restrict__ in, unsigned short* __restrict__ out, int R, int C) {
    __shared__ float tile[32][33];
    int c0 = blockIdx.x * 32, r0 = blockIdx.y * 32;
    int tx = threadIdx.x, ty = threadIdx.y;  // block 32x8
#pragma unroll
    for (int i = 0; i < 32; i += 8)
        tile[ty + i][tx] = in[(long)(r0 + ty + i) * C + c0 + tx];
    __syncthreads();
#pragma unroll
    for (int i = 0; i < 32; i += 8)
        out[(long)(c0 + ty + i) * R + r0 + tx] = f2bf(tile[tx][ty + i]);
}

// ---------------- GEMM: C[M][N] = A[M][K] * Bt[N][K]^T + bias ----------------
// m97 structure: 128x128 tile, BK=32, 4 waves (each 64x64), global_load_lds w=16.
template <bool OUT_BF16>
__global__ __launch_bounds__(256) void gemm_bt_kernel(
    const unsigned short* __restrict__ A,   // [M][K] bf16
    const unsigned short* __restrict__ Bt,  // [N][K] bf16
    const float* __restrict__ bias,         // [N]
    void* __restrict__ Cout,
    int M, int Nn, int K)
{
    __shared__ unsigned short As[128 * 32];
    __shared__ unsigned short Bs[128 * 32];

    const int t  = threadIdx.x;
    const int l  = t & 63;
    const int w  = t >> 6;
    const int wr = w >> 1, wc = w & 1;
    const int tr = blockIdx.y, tc = blockIdx.x;
    const int lrow = l & 15, lk = l >> 4;

    f32x4 acc[4][4] = {};

    const int r0  = t >> 2;      // staging row for chunk c=t (4 chunks of 8 bf16 per row)
    const int ch0 = t & 3;
    const long arow_base = (long)(tr * 128) * K;
    const long brow_base = (long)(tc * 128) * K;

    const int nk = K >> 5;
    for (int kt = 0; kt < nk; ++kt) {
        const int kb = kt * 32;
        gload_lds16(A  + arow_base + (long)r0 * K        + kb + ch0 * 8, &As[t * 8]);
        gload_lds16(A  + arow_base + (long)(r0 + 64) * K + kb + ch0 * 8, &As[(t + 256) * 8]);
        gload_lds16(Bt + brow_base + (long)r0 * K        + kb + ch0 * 8, &Bs[t * 8]);
        gload_lds16(Bt + brow_base + (long)(r0 + 64) * K + kb + ch0 * 8, &Bs[(t + 256) * 8]);
        __syncthreads();

        bf16x8 a[4], bb[4];
#pragma unroll
        for (int mi = 0; mi < 4; ++mi)
            a[mi] = *(const bf16x8*)&As[(wr * 64 + mi * 16 + lrow) * 32 + lk * 8];
#pragma unroll
        for (int ni = 0; ni < 4; ++ni)
            bb[ni] = *(const bf16x8*)&Bs[(wc * 64 + ni * 16 + lrow) * 32 + lk * 8];
#pragma unroll
        for (int mi = 0; mi < 4; ++mi)
#pragma unroll
            for (int ni = 0; ni < 4; ++ni)
                acc[mi][ni] = __builtin_amdgcn_mfma_f32_16x16x32_bf16(a[mi], bb[ni], acc[mi][ni], 0, 0, 0);
        __syncthreads();
    }

    const int row_base = tr * 128 + wr * 64;
    const int col_base = tc * 128 + wc * 64;
    float bv[4];
#pragma unroll
    for (int ni = 0; ni < 4; ++ni) bv[ni] = bias[col_base + ni * 16 + lrow];

#pragma unroll
    for (int mi = 0; mi < 4; ++mi)
#pragma unroll
        for (int ni = 0; ni < 4; ++ni)
#pragma unroll
            for (int r = 0; r < 4; ++r) {
                int row = row_base + mi * 16 + lk * 4 + r;
                int col = col_base + ni * 16 + lrow;
                float v = acc[mi][ni][r] + bv[ni];
                if (OUT_BF16) ((unsigned short*)Cout)[(long)row * Nn + col] = f2bf(v);
                else          ((float*)Cout)[(long)row * Nn + col] = v;
            }
}

// ---------------- fused flash attention ----------------
// block: 256 threads = 4 waves; each wave owns 16 q-rows; KV tiles of 64.
__global__ __launch_bounds__(256) void attn_kernel(
    const unsigned short* __restrict__ qkv,  // [MTOT][TD]; Q at h*64, K at 1024+h*64, V at 2048+h*64
    unsigned short* __restrict__ aout)       // [MTOT][DIM], col = h*64+d
{
    constexpr int KVB  = 64;
    constexpr int PADW = 72;   // row pad: 144B rows -> 2-way (free) conflicts on b128 reads
    __shared__ unsigned short Ks[KVB * PADW];    // [key][d]
    __shared__ unsigned short VsT[HD * PADW];    // [d][key]
    __shared__ unsigned short Plds[4 * 16 * PADW];

    const int t = threadIdx.x;
    const int l = t & 63;
    const int w = t >> 6;
    const int lrow = l & 15, lk = l >> 4;

    const int b  = blockIdx.y >> 4;
    const int h  = blockIdx.y & 15;
    const int q0 = blockIdx.x * 64 + w * 16;

    // Q fragments (held in registers for the whole KV loop)
    const long qrow = (long)(b * SEQ + q0 + lrow) * TD + h * HD;
    bf16x8 aq[2];
    aq[0] = *(const bf16x8*)&qkv[qrow + lk * 8];
    aq[1] = *(const bf16x8*)&qkv[qrow + 32 + lk * 8];

    f32x4 o[4] = {};
    float mrow[4], lsum[4];
#pragma unroll
    for (int r = 0; r < 4; ++r) { mrow[r] = -1e30f; lsum[r] = 0.f; }

    const int vch = t >> 5, vrp = t & 31;  // V staging: rows 2vrp,2vrp+1, d-chunk vch*8
    const long kbase = (long)(b * SEQ) * TD + DIM + h * HD;
    const long vbase = (long)(b * SEQ) * TD + 2 * DIM + h * HD;

    constexpr float SCL = 0.125f * 1.44269504f;  // 1/sqrt(64) * log2(e)

    for (int m0 = 0; m0 < SEQ; m0 += KVB) {
        // ---- stage K tile [64][64] ----
#pragma unroll
        for (int i = 0; i < 2; ++i) {
            int c = t + i * 256;
            int row = c & 63, ch = c >> 6;
            i32x4 v = *(const i32x4*)&qkv[kbase + (long)(m0 + row) * TD + ch * 8];
            *(i32x4*)&Ks[row * PADW + ch * 8] = v;
        }
        // ---- stage V transposed [d][key], packed row-pairs ----
        {
            const unsigned short* s0p = &qkv[vbase + (long)(m0 + 2 * vrp) * TD + vch * 8];
            i32x4 v0 = *(const i32x4*)s0p;
            i32x4 v1 = *(const i32x4*)(s0p + TD);
            const unsigned short* u0 = (const unsigned short*)&v0;
            const unsigned short* u1 = (const unsigned short*)&v1;
            unsigned int* V32 = (unsigned int*)VsT;  // [d][36]
#pragma unroll
            for (int j = 0; j < 8; ++j) {
                unsigned int word = (unsigned int)u0[j] | ((unsigned int)u1[j] << 16);
                V32[(vch * 8 + j) * 36 + vrp] = word;
            }
        }
        __syncthreads();

        // ---- QK^T: S[16 q][64 keys] ----
        f32x4 s[4];
#pragma unroll
        for (int f = 0; f < 4; ++f) {
            bf16x8 bk0 = *(const bf16x8*)&Ks[(f * 16 + lrow) * PADW + lk * 8];
            bf16x8 bk1 = *(const bf16x8*)&Ks[(f * 16 + lrow) * PADW + 32 + lk * 8];
            f32x4 z = {};
            z = __builtin_amdgcn_mfma_f32_16x16x32_bf16(aq[0], bk0, z, 0, 0, 0);
            z = __builtin_amdgcn_mfma_f32_16x16x32_bf16(aq[1], bk1, z, 0, 0, 0);
            s[f] = z;
        }

        // ---- online softmax (rows spread over 16-lane groups) ----
#pragma unroll
        for (int r = 0; r < 4; ++r) {
            float smax = fmaxf(fmaxf(s[0][r], s[1][r]), fmaxf(s[2][r], s[3][r])) * SCL;
#pragma unroll
            for (int msk = 1; msk < 16; msk <<= 1)
                smax = fmaxf(smax, __shfl_xor(smax, msk));
            float mnew = fmaxf(mrow[r], smax);
            float sc = exp2f(mrow[r] - mnew);
            mrow[r] = mnew;
            float psum = 0.f;
#pragma unroll
            for (int f = 0; f < 4; ++f) {
                float p = exp2f(s[f][r] * SCL - mnew);
                s[f][r] = p;
                psum += p;
            }
#pragma unroll
            for (int msk = 1; msk < 16; msk <<= 1)
                psum += __shfl_xor(psum, msk);
            lsum[r] = lsum[r] * sc + psum;
#pragma unroll
            for (int f = 0; f < 4; ++f) o[f][r] *= sc;
        }

        // ---- P -> LDS (per-wave private tile) ----
        unsigned short* P = &Plds[w * 16 * PADW];
#pragma unroll
        for (int f = 0; f < 4; ++f)
#pragma unroll
            for (int r = 0; r < 4; ++r)
                P[(lk * 4 + r) * PADW + f * 16 + lrow] = f2bf(s[f][r]);

        // ---- PV: O += P[16][64] * V[64][64] ----
        bf16x8 ap0 = *(const bf16x8*)&P[lrow * PADW + lk * 8];
        bf16x8 ap1 = *(const bf16x8*)&P[lrow * PADW + 32 + lk * 8];
#pragma unroll
        for (int f = 0; f < 4; ++f) {
            bf16x8 bv0 = *(const bf16x8*)&VsT[(f * 16 + lrow) * PADW + lk * 8];
            bf16x8 bv1 = *(const bf16x8*)&VsT[(f * 16 + lrow) * PADW + 32 + lk * 8];
            o[f] = __builtin_amdgcn_mfma_f32_16x16x32_bf16(ap0, bv0, o[f], 0, 0, 0);
            o[f] = __builtin_amdgcn_mfma_f32_16x16x32_bf16(ap1, bv1, o[f], 0, 0, 0);
        }
        __syncthreads();
    }

    // ---- normalize + store ----
    float inv[4];
#pragma unroll
    for (int r = 0; r < 4; ++r) inv[r] = 1.0f / lsum[r];
#pragma unroll
    for (int f = 0; f < 4; ++f)
#pragma unroll
        for (int r = 0; r < 4; ++r) {
            long orow = (long)(b * SEQ + q0 + lk * 4 + r);
            aout[orow * DIM + h * HD + f * 16 + lrow] = f2bf(o[f][r] * inv[r]);
        }
}

extern "C" void kernel_launch(void* const* d_in, const int* in_sizes, int n_in,
                              void* d_out, int out_size, void* d_ws, size_t ws_size,
                              hipStream_t stream)
{
    const float* x      = (const float*)d_in[0];
    const float* w_qkv  = (const float*)d_in[1];
    const float* b_qkv  = (const float*)d_in[2];
    const float* w_proj = (const float*)d_in[3];
    const float* b_proj = (const float*)d_in[4];
    float* out = (float*)d_out;

    unsigned short* x_bf   = (unsigned short*)d_ws;                 // 8192*1024
    unsigned short* wqkvT  = x_bf   + (size_t)MTOT * DIM;           // [3072][1024]
    unsigned short* wprojT = wqkvT  + (size_t)TD * DIM;             // [1024][1024]
    unsigned short* qkv    = wprojT + (size_t)DIM * DIM;            // [8192][3072]
    unsigned short* attn   = qkv    + (size_t)MTOT * TD;            // [8192][1024]

    cvt_kernel<<<2048, 256, 0, stream>>>(x, x_bf, MTOT * DIM / 4);
    dim3 tb(32, 8);
    transp_kernel<<<dim3(TD / 32, DIM / 32), tb, 0, stream>>>(w_qkv, wqkvT, DIM, TD);
    transp_kernel<<<dim3(DIM / 32, DIM / 32), tb, 0, stream>>>(w_proj, wprojT, DIM, DIM);

    gemm_bt_kernel<true><<<dim3(TD / 128, MTOT / 128), 256, 0, stream>>>(
        x_bf, wqkvT, b_qkv, qkv, MTOT, TD, DIM);

    attn_kernel<<<dim3(SEQ / 64, BATCH * NH), 256, 0, stream>>>(qkv, attn);

    gemm_bt_kernel<false><<<dim3(DIM / 128, MTOT / 128), 256, 0, stream>>>(
        attn, wprojT, b_proj, out, MTOT, DIM, DIM);
}

// Round 2
// 290.020 us; speedup vs baseline: 1.2661x; 1.2661x over previous
//
#include <hip/hip_runtime.h>
#include <hip/hip_bf16.h>

#define DEVI __device__ __forceinline__

typedef float f32x4 __attribute__((ext_vector_type(4)));
typedef short bf16x8 __attribute__((ext_vector_type(8)));
typedef int i32x4 __attribute__((ext_vector_type(4)));

constexpr int BATCH = 4;
constexpr int SEQ   = 2048;
constexpr int DIM   = 1024;
constexpr int NH    = 16;
constexpr int HD    = 64;
constexpr int TD    = 3 * DIM;       // 3072
constexpr int MTOT  = BATCH * SEQ;   // 8192

DEVI unsigned short f2bf(float f) {
    __hip_bfloat16 h = __float2bfloat16(f);   // native cvt, RNE
    return *reinterpret_cast<unsigned short*>(&h);
}

DEVI void gload_lds16(const unsigned short* gsrc, unsigned short* ldst) {
    __builtin_amdgcn_global_load_lds(
        (const __attribute__((address_space(1))) void*)gsrc,
        (__attribute__((address_space(3))) void*)ldst,
        16, 0, 0);
}

// ---------------- convert f32 -> bf16 ----------------
__global__ void cvt_kernel(const float* __restrict__ in, unsigned short* __restrict__ out, int n4) {
    int i = blockIdx.x * blockDim.x + threadIdx.x;
    int stride = gridDim.x * blockDim.x;
    for (; i < n4; i += stride) {
        float4 v = reinterpret_cast<const float4*>(in)[i];
        ushort4 o;
        o.x = f2bf(v.x); o.y = f2bf(v.y); o.z = f2bf(v.z); o.w = f2bf(v.w);
        reinterpret_cast<ushort4*>(out)[i] = o;
    }
}

// ---------------- transpose f32 [R][C] -> bf16 [C][R] ----------------
__global__ void transp_kernel(const float* __restrict__ in, unsigned short* __restrict__ out, int R, int C) {
    __shared__ float tile[32][33];
    int c0 = blockIdx.x * 32, r0 = blockIdx.y * 32;
    int tx = threadIdx.x, ty = threadIdx.y;  // block 32x8
#pragma unroll
    for (int i = 0; i < 32; i += 8)
        tile[ty + i][tx] = in[(long)(r0 + ty + i) * C + c0 + tx];
    __syncthreads();
#pragma unroll
    for (int i = 0; i < 32; i += 8)
        out[(long)(c0 + ty + i) * R + r0 + tx] = f2bf(tile[tx][ty + i]);
}

// ---------------- GEMM: C[M][N] = A[M][K] * Bt[N][K]^T + bias ----------------
// m97 structure: 128x128 tile, BK=32, 4 waves (each 64x64), global_load_lds w=16.
template <bool OUT_BF16>
__global__ __launch_bounds__(256) void gemm_bt_kernel(
    const unsigned short* __restrict__ A,   // [M][K] bf16
    const unsigned short* __restrict__ Bt,  // [N][K] bf16
    const float* __restrict__ bias,         // [N]
    void* __restrict__ Cout,
    int M, int Nn, int K)
{
    __shared__ unsigned short As[128 * 32];
    __shared__ unsigned short Bs[128 * 32];

    const int t  = threadIdx.x;
    const int l  = t & 63;
    const int w  = t >> 6;
    const int wr = w >> 1, wc = w & 1;
    const int tr = blockIdx.y, tc = blockIdx.x;
    const int lrow = l & 15, lk = l >> 4;

    f32x4 acc[4][4] = {};

    const int r0  = t >> 2;      // staging row for chunk c=t (4 chunks of 8 bf16 per row)
    const int ch0 = t & 3;
    const long arow_base = (long)(tr * 128) * K;
    const long brow_base = (long)(tc * 128) * K;

    const int nk = K >> 5;
    for (int kt = 0; kt < nk; ++kt) {
        const int kb = kt * 32;
        gload_lds16(A  + arow_base + (long)r0 * K        + kb + ch0 * 8, &As[t * 8]);
        gload_lds16(A  + arow_base + (long)(r0 + 64) * K + kb + ch0 * 8, &As[(t + 256) * 8]);
        gload_lds16(Bt + brow_base + (long)r0 * K        + kb + ch0 * 8, &Bs[t * 8]);
        gload_lds16(Bt + brow_base + (long)(r0 + 64) * K + kb + ch0 * 8, &Bs[(t + 256) * 8]);
        __syncthreads();

        bf16x8 a[4], bb[4];
#pragma unroll
        for (int mi = 0; mi < 4; ++mi)
            a[mi] = *(const bf16x8*)&As[(wr * 64 + mi * 16 + lrow) * 32 + lk * 8];
#pragma unroll
        for (int ni = 0; ni < 4; ++ni)
            bb[ni] = *(const bf16x8*)&Bs[(wc * 64 + ni * 16 + lrow) * 32 + lk * 8];
#pragma unroll
        for (int mi = 0; mi < 4; ++mi)
#pragma unroll
            for (int ni = 0; ni < 4; ++ni)
                acc[mi][ni] = __builtin_amdgcn_mfma_f32_16x16x32_bf16(a[mi], bb[ni], acc[mi][ni], 0, 0, 0);
        __syncthreads();
    }

    const int row_base = tr * 128 + wr * 64;
    const int col_base = tc * 128 + wc * 64;
    float bv[4];
#pragma unroll
    for (int ni = 0; ni < 4; ++ni) bv[ni] = bias[col_base + ni * 16 + lrow];

#pragma unroll
    for (int mi = 0; mi < 4; ++mi)
#pragma unroll
        for (int ni = 0; ni < 4; ++ni)
#pragma unroll
            for (int r = 0; r < 4; ++r) {
                int row = row_base + mi * 16 + lk * 4 + r;
                int col = col_base + ni * 16 + lrow;
                float v = acc[mi][ni][r] + bv[ni];
                if (OUT_BF16) ((unsigned short*)Cout)[(long)row * Nn + col] = f2bf(v);
                else          ((float*)Cout)[(long)row * Nn + col] = v;
            }
}

// ---------------- fused flash attention (swapped-operand form) ----------------
// block: 256 threads = 4 waves; each wave owns 16 q-rows; KV tiles of 64.
// QK^T computed swapped: S^T = mfma(K, Q) -> lane holds a full key-slice of one
// q-column (col = lane&15 = q). Softmax is serial in-lane + 2 shfl_xor across
// the 4 lk-groups. O accumulated transposed: O^T = mfma(V^T, P^T).
__global__ __launch_bounds__(256) void attn_kernel(
    const unsigned short* __restrict__ qkv,  // [MTOT][TD]; Q at h*64, K at 1024+h*64, V at 2048+h*64
    unsigned short* __restrict__ aout)       // [MTOT][DIM], col = h*64+d
{
    constexpr int KVB  = 64;
    constexpr int PADW = 72;   // 144B rows, 16B-aligned; ~2-way (free) conflicts on b128 reads
    __shared__ unsigned short Ks[KVB * PADW];    // [key][d]
    __shared__ unsigned short VsT[HD * PADW];    // [d][key]
    __shared__ unsigned short Plds[4 * 16 * PADW];  // per-wave [q][key]

    const int t = threadIdx.x;
    const int l = t & 63;
    const int w = t >> 6;
    const int lrow = l & 15, lk = l >> 4;

    const int b  = blockIdx.y >> 4;
    const int h  = blockIdx.y & 15;
    const int q0 = blockIdx.x * 64 + w * 16;

    // Q fragments as the B-operand (n = q = lane&15, k = d = lk*8+j)
    const long qrow = (long)(b * SEQ + q0 + lrow) * TD + h * HD;
    bf16x8 bq[2];
    bq[0] = *(const bf16x8*)&qkv[qrow + lk * 8];
    bq[1] = *(const bf16x8*)&qkv[qrow + 32 + lk * 8];

    f32x4 o[4] = {};                 // O^T fragments: lane holds q=lrow, d = 16*f2 + 4*lk + r
    float mrun = -1e30f, lsum = 0.f; // scalar per lane (one q-column)

    const int vch = t >> 5, vrp = t & 31;  // V staging: rows 2vrp,2vrp+1, d-chunk vch*8
    const long kbase = (long)(b * SEQ) * TD + DIM + h * HD;
    const long vbase = (long)(b * SEQ) * TD + 2 * DIM + h * HD;

    constexpr float SCL = 0.125f * 1.44269504f;  // 1/sqrt(64) * log2(e)

    unsigned short* P = &Plds[w * 16 * PADW];

    for (int m0 = 0; m0 < SEQ; m0 += KVB) {
        // ---- stage K tile [64][64] ----
#pragma unroll
        for (int i = 0; i < 2; ++i) {
            int c = t + i * 256;
            int row = c & 63, ch = c >> 6;
            i32x4 v = *(const i32x4*)&qkv[kbase + (long)(m0 + row) * TD + ch * 8];
            *(i32x4*)&Ks[row * PADW + ch * 8] = v;
        }
        // ---- stage V transposed [d][key], packed row-pairs ----
        {
            const unsigned short* s0p = &qkv[vbase + (long)(m0 + 2 * vrp) * TD + vch * 8];
            i32x4 v0 = *(const i32x4*)s0p;
            i32x4 v1 = *(const i32x4*)(s0p + TD);
            const unsigned short* u0 = (const unsigned short*)&v0;
            const unsigned short* u1 = (const unsigned short*)&v1;
            unsigned int* V32 = (unsigned int*)VsT;  // [d][36]
#pragma unroll
            for (int j = 0; j < 8; ++j) {
                unsigned int word = (unsigned int)u0[j] | ((unsigned int)u1[j] << 16);
                V32[(vch * 8 + j) * 36 + vrp] = word;
            }
        }
        __syncthreads();

        // ---- QK^T swapped: S^T[key][q]; lane holds keys 16f+4lk+r for q=lrow ----
        f32x4 s[4];
#pragma unroll
        for (int f = 0; f < 4; ++f) {
            bf16x8 ak0 = *(const bf16x8*)&Ks[(f * 16 + lrow) * PADW + lk * 8];
            bf16x8 ak1 = *(const bf16x8*)&Ks[(f * 16 + lrow) * PADW + 32 + lk * 8];
            f32x4 z = {};
            z = __builtin_amdgcn_mfma_f32_16x16x32_bf16(ak0, bq[0], z, 0, 0, 0);
            z = __builtin_amdgcn_mfma_f32_16x16x32_bf16(ak1, bq[1], z, 0, 0, 0);
            s[f] = z;
        }

        // ---- online softmax: serial in-lane + 2 shfl_xor over lk-groups ----
        float v0m = fmaxf(fmaxf(s[0][0], s[0][1]), fmaxf(s[0][2], s[0][3]));
        float v1m = fmaxf(fmaxf(s[1][0], s[1][1]), fmaxf(s[1][2], s[1][3]));
        float v2m = fmaxf(fmaxf(s[2][0], s[2][1]), fmaxf(s[2][2], s[2][3]));
        float v3m = fmaxf(fmaxf(s[3][0], s[3][1]), fmaxf(s[3][2], s[3][3]));
        float vmax = fmaxf(fmaxf(v0m, v1m), fmaxf(v2m, v3m));
        vmax = fmaxf(vmax, __shfl_xor(vmax, 16));
        vmax = fmaxf(vmax, __shfl_xor(vmax, 32));

        float mnew = fmaxf(mrun, vmax * SCL);
        float sc = exp2f(mrun - mnew);
        mrun = mnew;

        float ps = 0.f;
#pragma unroll
        for (int f = 0; f < 4; ++f)
#pragma unroll
            for (int r = 0; r < 4; ++r) {
                float p = exp2f(s[f][r] * SCL - mnew);
                s[f][r] = p;
                ps += p;
            }
        ps += __shfl_xor(ps, 16);
        ps += __shfl_xor(ps, 32);
        lsum = lsum * sc + ps;

#pragma unroll
        for (int f2 = 0; f2 < 4; ++f2)
#pragma unroll
            for (int r = 0; r < 4; ++r) o[f2][r] *= sc;

        // ---- P -> LDS as [q][key] rows (wave-private), packed 32-bit writes ----
#pragma unroll
        for (int f = 0; f < 4; ++f)
#pragma unroll
            for (int rr = 0; rr < 2; ++rr) {
                ushort2 wd;
                wd.x = f2bf(s[f][2 * rr]);
                wd.y = f2bf(s[f][2 * rr + 1]);
                *(ushort2*)&P[lrow * PADW + f * 16 + lk * 4 + 2 * rr] = wd;
            }

        // ---- PV transposed: O^T += V^T[d][k] * P^T[k][q] ----
        bf16x8 pb0 = *(const bf16x8*)&P[lrow * PADW + lk * 8];
        bf16x8 pb1 = *(const bf16x8*)&P[lrow * PADW + 32 + lk * 8];
#pragma unroll
        for (int f2 = 0; f2 < 4; ++f2) {
            bf16x8 av0 = *(const bf16x8*)&VsT[(f2 * 16 + lrow) * PADW + lk * 8];
            bf16x8 av1 = *(const bf16x8*)&VsT[(f2 * 16 + lrow) * PADW + 32 + lk * 8];
            o[f2] = __builtin_amdgcn_mfma_f32_16x16x32_bf16(av0, pb0, o[f2], 0, 0, 0);
            o[f2] = __builtin_amdgcn_mfma_f32_16x16x32_bf16(av1, pb1, o[f2], 0, 0, 0);
        }
        __syncthreads();
    }

    // ---- normalize + store (lane holds q=lrow, d = 16*f2 + 4*lk + r) ----
    float inv = 1.0f / lsum;
    const long orow = (long)(b * SEQ + q0 + lrow);
#pragma unroll
    for (int f2 = 0; f2 < 4; ++f2) {
        ushort4 st;
        st.x = f2bf(o[f2][0] * inv);
        st.y = f2bf(o[f2][1] * inv);
        st.z = f2bf(o[f2][2] * inv);
        st.w = f2bf(o[f2][3] * inv);
        *(ushort4*)&aout[orow * DIM + h * HD + f2 * 16 + lk * 4] = st;
    }
}

extern "C" void kernel_launch(void* const* d_in, const int* in_sizes, int n_in,
                              void* d_out, int out_size, void* d_ws, size_t ws_size,
                              hipStream_t stream)
{
    const float* x      = (const float*)d_in[0];
    const float* w_qkv  = (const float*)d_in[1];
    const float* b_qkv  = (const float*)d_in[2];
    const float* w_proj = (const float*)d_in[3];
    const float* b_proj = (const float*)d_in[4];
    float* out = (float*)d_out;

    unsigned short* x_bf   = (unsigned short*)d_ws;                 // 8192*1024
    unsigned short* wqkvT  = x_bf   + (size_t)MTOT * DIM;           // [3072][1024]
    unsigned short* wprojT = wqkvT  + (size_t)TD * DIM;             // [1024][1024]
    unsigned short* qkv    = wprojT + (size_t)DIM * DIM;            // [8192][3072]
    unsigned short* attn   = qkv    + (size_t)MTOT * TD;            // [8192][1024]

    cvt_kernel<<<2048, 256, 0, stream>>>(x, x_bf, MTOT * DIM / 4);
    dim3 tb(32, 8);
    transp_kernel<<<dim3(TD / 32, DIM / 32), tb, 0, stream>>>(w_qkv, wqkvT, DIM, TD);
    transp_kernel<<<dim3(DIM / 32, DIM / 32), tb, 0, stream>>>(w_proj, wprojT, DIM, DIM);

    gemm_bt_kernel<true><<<dim3(TD / 128, MTOT / 128), 256, 0, stream>>>(
        x_bf, wqkvT, b_qkv, qkv, MTOT, TD, DIM);

    attn_kernel<<<dim3(SEQ / 64, BATCH * NH), 256, 0, stream>>>(qkv, attn);

    gemm_bt_kernel<false><<<dim3(DIM / 128, MTOT / 128), 256, 0, stream>>>(
        attn, wprojT, b_proj, out, MTOT, DIM, DIM);
}